// Round 8
// baseline (705.839 us; speedup 1.0000x reference)
//
#include <hip/hip_runtime.h>

#define D     128
#define NT    200000
#define NL    50000
#define ETA   1000000
#define EREV  1000000
#define ELL   500000
#define ELBL  500000
#define DD    (D * D)

// Bucketed CSR build parameters.
#define NBK   256                    // buckets per relation
#define CH    8192                   // edges per chunk block
#define NCH_TA  ((ETA  + CH - 1) / CH)   // 123
#define NCH_LL  ((ELL  + CH - 1) / CH)   // 62
#define NCH_REV ((EREV + CH - 1) / CH)   // 123
#define R_TA  ((NL + NBK - 1) / NBK)     // 196 rows per bucket
#define R_LL  R_TA
#define R_REV ((NT + NBK - 1) / NBK)     // 782
#define RMAX  800

typedef __attribute__((ext_vector_type(8))) __bf16 bf16x8;
typedef __attribute__((ext_vector_type(4))) float f32x4;
typedef __attribute__((ext_vector_type(2))) _Float16 f16x2;
typedef __attribute__((ext_vector_type(4))) _Float16 f16x4;
typedef __attribute__((ext_vector_type(8))) _Float16 f16x8;

__device__ inline bf16x8 cvt8(float4 a, float4 b)
{
    bf16x8 r;
    r[0] = (__bf16)a.x; r[1] = (__bf16)a.y; r[2] = (__bf16)a.z; r[3] = (__bf16)a.w;
    r[4] = (__bf16)b.x; r[5] = (__bf16)b.y; r[6] = (__bf16)b.z; r[7] = (__bf16)b.w;
    return r;
}

__device__ inline f16x8 pack8(const f32x4& a, const f32x4& b)
{
    f16x8 o;
    o[0] = (_Float16)a[0]; o[1] = (_Float16)a[1];
    o[2] = (_Float16)a[2]; o[3] = (_Float16)a[3];
    o[4] = (_Float16)b[0]; o[5] = (_Float16)b[1];
    o[6] = (_Float16)b[2]; o[7] = (_Float16)b[3];
    return o;
}

// ---------------------------------------------------------------------------
// Z/mean tables: PERMUTED per-row layout matching the MFMA C-fragment:
//   perm[row][q*32 + nt*4 + i] == logical[row][nt*16 + q*4 + i]
// Weights: FRAGMENT-ORDERED bf16 (frag f=kc*8+nt at [f*64+lane]).
// ---------------------------------------------------------------------------

__global__ __launch_bounds__(256) void prep_weights(
    const float* __restrict__ Wl_tl, const float* __restrict__ Wr_tl,
    const float* __restrict__ Wl_ll, const float* __restrict__ Wr_ll,
    const float* __restrict__ b_tl, const float* __restrict__ b_ll,
    __bf16* __restrict__ Wb, float* __restrict__ bias_sum)
{
    int i = blockIdx.x * 256 + threadIdx.x;
    if (i < DD) {
        int n = i >> 7, k = i & 127;
        int kc = k >> 5, q = (k >> 3) & 3, j = k & 7;
        int nt = n >> 4, m15 = n & 15;
        int dst = (((kc * 8 + nt) * 4 + q) * 16 + m15) * 8 + j;
        Wb[dst]          = (__bf16)Wl_tl[i];
        Wb[DD + dst]     = (__bf16)Wr_tl[i];
        Wb[2 * DD + dst] = (__bf16)Wl_ll[i];
        Wb[3 * DD + dst] = (__bf16)(Wr_tl[i] + Wr_ll[i]);
    }
    if (i < D) bias_sum[i] = b_tl[i] + b_ll[i];
}

// ---------------------------------------------------------------------------
// Pass A1: per-chunk bucket histograms (LDS atomics only).
// ---------------------------------------------------------------------------
__global__ __launch_bounds__(256) void part_count(
    const int* __restrict__ taD, const int* __restrict__ llD,
    const int* __restrict__ revD,
    int* __restrict__ MTa, int* __restrict__ MLl, int* __restrict__ MRev)
{
    __shared__ int h[NBK];
    int bb = blockIdx.x, tid = threadIdx.x;
    const int* dst; int E, R, chunk; int* M;
    if (bb < NCH_TA) { dst = taD; E = ETA; R = R_TA; M = MTa; chunk = bb; }
    else if (bb < NCH_TA + NCH_LL) { dst = llD; E = ELL; R = R_LL; M = MLl; chunk = bb - NCH_TA; }
    else { dst = revD; E = EREV; R = R_REV; M = MRev; chunk = bb - NCH_TA - NCH_LL; }

    h[tid] = 0;
    __syncthreads();
    int eBeg = chunk * CH, eEnd = min(E, eBeg + CH);
    for (int e = eBeg + tid; e < eEnd; e += 256)
        atomicAdd(&h[dst[e] / R], 1);
    __syncthreads();
    M[chunk * NBK + tid] = h[tid];
}

// ---------------------------------------------------------------------------
// Pass A2: column scan of the chunk x bucket matrix (one block per relation).
// ---------------------------------------------------------------------------
__global__ __launch_bounds__(256) void part_scan(
    int* __restrict__ MTa, int* __restrict__ MLl, int* __restrict__ MRev,
    int* __restrict__ bsTa, int* __restrict__ bsLl, int* __restrict__ bsRev)
{
    int rel = blockIdx.x, tid = threadIdx.x;
    int* M; int nCh; int* bs;
    if (rel == 0) { M = MTa; nCh = NCH_TA; bs = bsTa; }
    else if (rel == 1) { M = MLl; nCh = NCH_LL; bs = bsLl; }
    else { M = MRev; nCh = NCH_REV; bs = bsRev; }

    int run = 0;
    for (int c = 0; c < nCh; ++c) {
        int v = M[c * NBK + tid];
        M[c * NBK + tid] = run;
        run += v;
    }
    int lane = tid & 63, w = tid >> 6;
    int incl = run;
#pragma unroll
    for (int off = 1; off < 64; off <<= 1) {
        int v = __shfl_up(incl, off, 64);
        if (lane >= off) incl += v;
    }
    __shared__ int ws[4];
    if (lane == 63) ws[w] = incl;
    __syncthreads();
    int base = 0;
    for (int j = 0; j < w; ++j) base += ws[j];
    int excl = base + incl - run;
    bs[tid] = excl;
    if (tid == 255) bs[NBK] = excl + run;
}

// ---------------------------------------------------------------------------
// Pass A3: scatter edges into bucketed (src,dst) pair lists. LDS cursors.
// ---------------------------------------------------------------------------
__global__ __launch_bounds__(256) void part_scatter(
    const int* __restrict__ taS, const int* __restrict__ taD,
    const int* __restrict__ llS, const int* __restrict__ llD,
    const int* __restrict__ revS, const int* __restrict__ revD,
    const int* __restrict__ MTa, const int* __restrict__ MLl,
    const int* __restrict__ MRev,
    const int* __restrict__ bsTa, const int* __restrict__ bsLl,
    const int* __restrict__ bsRev,
    int2* __restrict__ pTa, int2* __restrict__ pLl, int2* __restrict__ pRev)
{
    __shared__ int cur[NBK];
    int bb = blockIdx.x, tid = threadIdx.x;
    const int *src, *dst, *M, *bs; int E, R, chunk; int2* pr;
    if (bb < NCH_TA) {
        src = taS; dst = taD; M = MTa; bs = bsTa; pr = pTa;
        E = ETA; R = R_TA; chunk = bb;
    } else if (bb < NCH_TA + NCH_LL) {
        src = llS; dst = llD; M = MLl; bs = bsLl; pr = pLl;
        E = ELL; R = R_LL; chunk = bb - NCH_TA;
    } else {
        src = revS; dst = revD; M = MRev; bs = bsRev; pr = pRev;
        E = EREV; R = R_REV; chunk = bb - NCH_TA - NCH_LL;
    }
    cur[tid] = bs[tid] + M[chunk * NBK + tid];
    __syncthreads();
    int eBeg = chunk * CH, eEnd = min(E, eBeg + CH);
    for (int e = eBeg + tid; e < eEnd; e += 256) {
        int d = dst[e], s = src[e];
        int pos = atomicAdd(&cur[d / R], 1);
        pr[pos] = make_int2(s, d);
    }
}

// ---------------------------------------------------------------------------
// Pass B: per-bucket CSR build (LDS histogram + prefix + LDS-ticket scatter).
// ---------------------------------------------------------------------------
__global__ __launch_bounds__(256) void csr_build(
    const int2* __restrict__ pTa, const int* __restrict__ bsTa,
    int* __restrict__ cntTa, int* __restrict__ curTa, int* __restrict__ csrTa,
    const int2* __restrict__ pLl, const int* __restrict__ bsLl,
    int* __restrict__ cntLl, int* __restrict__ curLl, int* __restrict__ csrLl,
    const int2* __restrict__ pRev, const int* __restrict__ bsRev,
    int* __restrict__ cntRev, int* __restrict__ curRev, int* __restrict__ csrRev)
{
    __shared__ int counts[RMAX];
    __shared__ int starts[RMAX];
    __shared__ int ws[4];
    int bb = blockIdx.x, tid = threadIdx.x;
    const int2* pr; const int* bs; int *cnt, *cur, *csr; int R, n;
    if (bb < NBK) {
        pr = pTa; bs = bsTa; cnt = cntTa; cur = curTa; csr = csrTa;
        R = R_TA; n = NL;
    } else if (bb < 2 * NBK) {
        bb -= NBK;
        pr = pLl; bs = bsLl; cnt = cntLl; cur = curLl; csr = csrLl;
        R = R_LL; n = NL;
    } else {
        bb -= 2 * NBK;
        pr = pRev; bs = bsRev; cnt = cntRev; cur = curRev; csr = csrRev;
        R = R_REV; n = NT;
    }
    const int rowBase = bb * R;
    const int eBeg = bs[bb], eEnd = bs[bb + 1];
    const int K = (R + 255) / 256;

    for (int k = 0; k < K; ++k) {
        int r = tid * K + k;
        if (r < R) counts[r] = 0;
    }
    __syncthreads();
    for (int e = eBeg + tid; e < eEnd; e += 256)
        atomicAdd(&counts[pr[e].y - rowBase], 1);
    __syncthreads();

    int local[4]; int sum = 0;
    for (int k = 0; k < K; ++k) {
        int r = tid * K + k;
        int v = (r < R) ? counts[r] : 0;
        local[k] = sum;
        sum += v;
    }
    int lane = tid & 63, w = tid >> 6;
    int incl = sum;
#pragma unroll
    for (int off = 1; off < 64; off <<= 1) {
        int v = __shfl_up(incl, off, 64);
        if (lane >= off) incl += v;
    }
    if (lane == 63) ws[w] = incl;
    __syncthreads();
    int wbase = 0;
    for (int j = 0; j < w; ++j) wbase += ws[j];
    int tbase = wbase + incl - sum;

    for (int k = 0; k < K; ++k) {
        int r = tid * K + k;
        if (r < R) {
            int v = counts[r];
            int excl = tbase + local[k];
            starts[r] = excl;
            int row = rowBase + r;
            if (row < n) {
                cnt[row] = v;
                cur[row] = eBeg + excl + v;
            }
        }
    }
    __syncthreads();

    for (int e = eBeg + tid; e < eEnd; e += 256) {
        int2 p = pr[e];
        int pos = eBeg + atomicAdd(&starts[p.y - rowBase], 1);
        csr[pos] = p.x;
    }
}

// ---------------------------------------------------------------------------
// rev mean, COLUMN-SPLIT: two passes of 64 permuted cols (128 B slices).
// A 256 B row gather is already 2 cache-line fetches, so the split costs no
// extra transactions — but shrinks the gathered working set to 6.4 MB/pass
// (vs 4 MiB per-XCD L2), converting L3 round-trips into L2 hits.
// Wave = one row-half; lane reads 1 f16 (64 lanes x 2 B = 128 B contiguous).
// Output fp32 permuted into the outTitle region (64 lanes x 4 B = 256 B).
// ---------------------------------------------------------------------------
#define HREV ((NT + 3) / 4)
__global__ __launch_bounds__(256) void agg_rev_kernel(
    const _Float16* __restrict__ Z, const int* __restrict__ csr,
    const int* __restrict__ cnt, const int* __restrict__ cur,
    float* __restrict__ outF)
{
    int bb = blockIdx.x;
    int half = (bb >= HREV);
    if (half) bb -= HREV;
    int row = bb * 4 + (threadIdx.x >> 6);
    if (row >= NT) return;
    int lane = threadIdx.x & 63;
    int c = half * 64 + lane;               // permuted col
    int deg = cnt[row];
    int end = cur[row];
    int e = end - deg;
    float ax = 0.f;
    for (; e + 3 < end; e += 4) {
        int s0 = csr[e], s1 = csr[e + 1], s2 = csr[e + 2], s3 = csr[e + 3];
        float v0 = (float)Z[(size_t)s0 * D + c];
        float v1 = (float)Z[(size_t)s1 * D + c];
        float v2 = (float)Z[(size_t)s2 * D + c];
        float v3 = (float)Z[(size_t)s3 * D + c];
        ax += v0 + v1 + v2 + v3;
    }
    for (; e < end; ++e)
        ax += (float)Z[(size_t)csr[e] * D + c];
    float r = 1.0f / fmaxf((float)deg, 1.0f);
    outF[(size_t)row * D + c] = ax * r;
}

// ---------------------------------------------------------------------------
// Fused ta + ll means (f16 out), block-granular split.
// ---------------------------------------------------------------------------
#define BTA ((NL + 3) / 4)
__global__ __launch_bounds__(256) void agg_ta_ll_kernel(
    const _Float16* __restrict__ Zta, const int* __restrict__ csrTa,
    const int* __restrict__ cntTa, const int* __restrict__ curTa,
    _Float16* __restrict__ meanTa,
    const _Float16* __restrict__ Zll, const int* __restrict__ csrLl,
    const int* __restrict__ cntLl, const int* __restrict__ curLl,
    _Float16* __restrict__ meanLl)
{
    int b = blockIdx.x;
    const _Float16* Z; const int *csr, *cnt, *cur; _Float16* o;
    if (b < BTA) { Z = Zta; csr = csrTa; cnt = cntTa; cur = curTa; o = meanTa; }
    else { b -= BTA; Z = Zll; csr = csrLl; cnt = cntLl; cur = curLl; o = meanLl; }
    int row = b * 4 + (threadIdx.x >> 6);
    if (row >= NL) return;
    int lane = threadIdx.x & 63;
    int deg = cnt[row];
    int end = cur[row];
    int e = end - deg;
    float ax = 0.f, ay = 0.f;
    for (; e + 3 < end; e += 4) {
        int s0 = csr[e], s1 = csr[e + 1], s2 = csr[e + 2], s3 = csr[e + 3];
        f16x2 v0 = *reinterpret_cast<const f16x2*>(Z + (size_t)s0 * D + lane * 2);
        f16x2 v1 = *reinterpret_cast<const f16x2*>(Z + (size_t)s1 * D + lane * 2);
        f16x2 v2 = *reinterpret_cast<const f16x2*>(Z + (size_t)s2 * D + lane * 2);
        f16x2 v3 = *reinterpret_cast<const f16x2*>(Z + (size_t)s3 * D + lane * 2);
        ax += (float)v0[0] + (float)v1[0] + (float)v2[0] + (float)v3[0];
        ay += (float)v0[1] + (float)v1[1] + (float)v2[1] + (float)v3[1];
    }
    for (; e < end; ++e) {
        int s0 = csr[e];
        f16x2 v0 = *reinterpret_cast<const f16x2*>(Z + (size_t)s0 * D + lane * 2);
        ax += (float)v0[0];
        ay += (float)v0[1];
    }
    float r = 1.0f / fmaxf((float)deg, 1.0f);
    f16x2 ov; ov[0] = (_Float16)(ax * r); ov[1] = (_Float16)(ay * r);
    *reinterpret_cast<f16x2*>(o + (size_t)row * D + lane * 2) = ov;
}

// ---------------------------------------------------------------------------
// Zrev/Zll = x_label @ {W_l_tl, W_l_ll}^T, fp16 permuted. W0+W2 in LDS.
// 512 threads / 128 rows per block (2 blocks/CU -> 16 waves/CU).
// ---------------------------------------------------------------------------
__global__ __launch_bounds__(512) void z_label_gemm(
    const float* __restrict__ labelEmbed, const int* __restrict__ labelNodeId,
    const __bf16* __restrict__ Wb,
    _Float16* __restrict__ Zrev, _Float16* __restrict__ Zll)
{
    __shared__ __bf16 sW[2 * DD];
    const int tid = threadIdx.x;
    const int lane = tid & 63;
    const int m15 = lane & 15, q = lane >> 4;
    const int rowOrig = blockIdx.x * 128 + (tid >> 6) * 16 + m15;
    const int row = (rowOrig < NL) ? rowOrig : NL - 1;
    const int xr = labelNodeId[row];

    const float* pe = labelEmbed + (size_t)xr * D + q * 8;
    float4 xf[8];
#pragma unroll
    for (int kc = 0; kc < 4; ++kc) {
        xf[2 * kc]     = *reinterpret_cast<const float4*>(pe + kc * 32);
        xf[2 * kc + 1] = *reinterpret_cast<const float4*>(pe + kc * 32 + 4);
    }
    {
        const float4* g0 = reinterpret_cast<const float4*>(Wb);
        const float4* g2 = reinterpret_cast<const float4*>(Wb + 2 * DD);
        float4* ls = reinterpret_cast<float4*>(sW);
        for (int it = tid; it < 2048; it += 512) {
            ls[it] = g0[it];
            ls[2048 + it] = g2[it];
        }
    }
    bf16x8 aE[4];
#pragma unroll
    for (int kc = 0; kc < 4; ++kc) aE[kc] = cvt8(xf[2 * kc], xf[2 * kc + 1]);
    __syncthreads();

    const bf16x8* wl = reinterpret_cast<const bf16x8*>(sW);
    const f32x4 z4 = {0.f, 0.f, 0.f, 0.f};
#pragma unroll
    for (int pass = 0; pass < 2; ++pass) {
        const int sb = pass ? 2048 : 0;
        _Float16* Z = pass ? Zll : Zrev;
        f32x4 acc[8];
#pragma unroll
        for (int nt = 0; nt < 8; ++nt) acc[nt] = z4;
#pragma unroll
        for (int kc = 0; kc < 4; ++kc)
#pragma unroll
            for (int nt = 0; nt < 8; ++nt)
                acc[nt] = __builtin_amdgcn_mfma_f32_16x16x32_bf16(
                    wl[sb + (kc * 8 + nt) * 64 + lane], aE[kc], acc[nt], 0, 0, 0);
        if (rowOrig < NL) {
            f16x8* zp = reinterpret_cast<f16x8*>(Z + (size_t)row * D + q * 32);
#pragma unroll
            for (int k = 0; k < 4; ++k)
                zp[k] = pack8(acc[2 * k], acc[2 * k + 1]);
        }
    }
}

// ---------------------------------------------------------------------------
// Title GEMM (W0+W1 in LDS): Zta + outTitle(+meanRev)+Zot.
// 512 threads / 128 rows per block: 64 KiB LDS -> 2 blocks/CU but now
// 16 waves/CU (was 8) — doubles latency-hiding for the streaming loads.
// ---------------------------------------------------------------------------
__global__ __launch_bounds__(512) void gemm_title_mfma(
    const float* __restrict__ xTitle, const __bf16* __restrict__ Wb,
    const float* __restrict__ b_tl,
    _Float16* __restrict__ Zta, _Float16* __restrict__ Zot,
    float* outTitle /* also meanRev input — no restrict */)
{
    __shared__ __bf16 sW[2 * DD];
    const int tid = threadIdx.x;
    const int lane = tid & 63;
    const int m15 = lane & 15, q = lane >> 4;
    const int rowOrig = blockIdx.x * 128 + (tid >> 6) * 16 + m15;
    const int row = (rowOrig < NT) ? rowOrig : NT - 1;

    const float* px = xTitle + (size_t)row * D + q * 8;
    float4 xf[8];
#pragma unroll
    for (int kc = 0; kc < 4; ++kc) {
        xf[2 * kc]     = *reinterpret_cast<const float4*>(px + kc * 32);
        xf[2 * kc + 1] = *reinterpret_cast<const float4*>(px + kc * 32 + 4);
    }
    {
        const float4* gs = reinterpret_cast<const float4*>(Wb);
        float4* ls = reinterpret_cast<float4*>(sW);
        for (int it = tid; it < 4096; it += 512) ls[it] = gs[it];
    }
    bf16x8 aX[4];
#pragma unroll
    for (int kc = 0; kc < 4; ++kc) aX[kc] = cvt8(xf[2 * kc], xf[2 * kc + 1]);

    f32x4 mr[8];
    {
        const f32x4* mp = reinterpret_cast<const f32x4*>(outTitle + (size_t)row * D + q * 32);
#pragma unroll
        for (int c = 0; c < 8; ++c) mr[c] = mp[c];
    }
    __syncthreads();

    const bf16x8* wl = reinterpret_cast<const bf16x8*>(sW);
    const f32x4 z4 = {0.f, 0.f, 0.f, 0.f};
    f32x4 acc[8];

    // Pass 1: W0 -> Zta.
#pragma unroll
    for (int nt = 0; nt < 8; ++nt) acc[nt] = z4;
#pragma unroll
    for (int kc = 0; kc < 4; ++kc)
#pragma unroll
        for (int nt = 0; nt < 8; ++nt)
            acc[nt] = __builtin_amdgcn_mfma_f32_16x16x32_bf16(
                wl[(kc * 8 + nt) * 64 + lane], aX[kc], acc[nt], 0, 0, 0);
    if (rowOrig < NT) {
        f16x8* zp = reinterpret_cast<f16x8*>(Zta + (size_t)row * D + q * 32);
#pragma unroll
        for (int k = 0; k < 4; ++k)
            zp[k] = pack8(acc[2 * k], acc[2 * k + 1]);
    }

    // Pass 2: W1 + meanRev + bias + relu.
#pragma unroll
    for (int nt = 0; nt < 8; ++nt) acc[nt] = z4;
#pragma unroll
    for (int kc = 0; kc < 4; ++kc)
#pragma unroll
        for (int nt = 0; nt < 8; ++nt)
            acc[nt] = __builtin_amdgcn_mfma_f32_16x16x32_bf16(
                wl[2048 + (kc * 8 + nt) * 64 + lane], aX[kc], acc[nt], 0, 0, 0);
#pragma unroll
    for (int c = 0; c < 8; ++c) {
        acc[c][0] += mr[c][0]; acc[c][1] += mr[c][1];
        acc[c][2] += mr[c][2]; acc[c][3] += mr[c][3];
    }
#pragma unroll
    for (int nt = 0; nt < 8; ++nt) {
        float4 bb = *reinterpret_cast<const float4*>(b_tl + nt * 16 + q * 4);
        acc[nt][0] = fmaxf(acc[nt][0] + bb.x, 0.0f);
        acc[nt][1] = fmaxf(acc[nt][1] + bb.y, 0.0f);
        acc[nt][2] = fmaxf(acc[nt][2] + bb.z, 0.0f);
        acc[nt][3] = fmaxf(acc[nt][3] + bb.w, 0.0f);
    }
    if (rowOrig < NT) {
#pragma unroll
        for (int nt = 0; nt < 8; ++nt)
            *reinterpret_cast<f32x4*>(outTitle + (size_t)row * D + nt * 16 + q * 4) = acc[nt];
        if (Zot) {
            f16x8* zp = reinterpret_cast<f16x8*>(Zot + (size_t)row * D + q * 32);
#pragma unroll
            for (int k = 0; k < 4; ++k)
                zp[k] = pack8(acc[2 * k], acc[2 * k + 1]);
        }
    }
}

// ---------------------------------------------------------------------------
// Label GEMM (W3 in LDS, 32 KiB): outLabel + Zol.
// ---------------------------------------------------------------------------
__global__ __launch_bounds__(256) void gemm_label_mfma(
    const float* __restrict__ labelEmbed, const int* __restrict__ labelNodeId,
    const __bf16* __restrict__ Wb, const float* __restrict__ bias_sum,
    const _Float16* __restrict__ meanTa, const _Float16* __restrict__ meanLl,
    float* __restrict__ outLabel, _Float16* __restrict__ Zol)
{
    __shared__ __bf16 sW[DD];
    const int tid = threadIdx.x;
    const int lane = tid & 63;
    const int m15 = lane & 15, q = lane >> 4;
    const int rowOrig = blockIdx.x * 64 + (tid >> 6) * 16 + m15;
    const int row = (rowOrig < NL) ? rowOrig : NL - 1;
    const int xr = labelNodeId[row];

    const float* pe = labelEmbed + (size_t)xr * D + q * 8;
    float4 xf[8];
#pragma unroll
    for (int kc = 0; kc < 4; ++kc) {
        xf[2 * kc]     = *reinterpret_cast<const float4*>(pe + kc * 32);
        xf[2 * kc + 1] = *reinterpret_cast<const float4*>(pe + kc * 32 + 4);
    }
    {
        const float4* g3 = reinterpret_cast<const float4*>(Wb + 3 * DD);
        float4* ls = reinterpret_cast<float4*>(sW);
        for (int it = tid; it < 2048; it += 256) ls[it] = g3[it];
    }
    bf16x8 aXl[4];
#pragma unroll
    for (int kc = 0; kc < 4; ++kc) aXl[kc] = cvt8(xf[2 * kc], xf[2 * kc + 1]);

    f16x8 mt[4], ml[4];
    {
        const f16x8* pt = reinterpret_cast<const f16x8*>(meanTa + (size_t)row * D + q * 32);
        const f16x8* pl = reinterpret_cast<const f16x8*>(meanLl + (size_t)row * D + q * 32);
#pragma unroll
        for (int k = 0; k < 4; ++k) { mt[k] = pt[k]; ml[k] = pl[k]; }
    }
    __syncthreads();

    const bf16x8* wl = reinterpret_cast<const bf16x8*>(sW);
    const f32x4 z4 = {0.f, 0.f, 0.f, 0.f};
    f32x4 acc[8];
#pragma unroll
    for (int nt = 0; nt < 8; ++nt) acc[nt] = z4;
#pragma unroll
    for (int kc = 0; kc < 4; ++kc)
#pragma unroll
        for (int nt = 0; nt < 8; ++nt)
            acc[nt] = __builtin_amdgcn_mfma_f32_16x16x32_bf16(
                wl[(kc * 8 + nt) * 64 + lane], aXl[kc], acc[nt], 0, 0, 0);

#pragma unroll
    for (int k = 0; k < 4; ++k) {
#pragma unroll
        for (int h = 0; h < 8; ++h) {
            int j = k * 8 + h;
            acc[j >> 2][j & 3] += (float)mt[k][h] + (float)ml[k][h];
        }
    }
#pragma unroll
    for (int nt = 0; nt < 8; ++nt) {
        float4 bb = *reinterpret_cast<const float4*>(bias_sum + nt * 16 + q * 4);
        acc[nt][0] = fmaxf(acc[nt][0] + bb.x, 0.0f);
        acc[nt][1] = fmaxf(acc[nt][1] + bb.y, 0.0f);
        acc[nt][2] = fmaxf(acc[nt][2] + bb.z, 0.0f);
        acc[nt][3] = fmaxf(acc[nt][3] + bb.w, 0.0f);
    }
    if (rowOrig < NL) {
#pragma unroll
        for (int nt = 0; nt < 8; ++nt)
            *reinterpret_cast<f32x4*>(outLabel + (size_t)row * D + nt * 16 + q * 4) = acc[nt];
        f16x8* zp = reinterpret_cast<f16x8*>(Zol + (size_t)row * D + q * 32);
#pragma unroll
        for (int k = 0; k < 4; ++k)
            zp[k] = pack8(acc[2 * k], acc[2 * k + 1]);
    }
}

// ---------------------------------------------------------------------------
// Supervision-edge dot products: 32 lanes/edge, f16 shadows both sides.
// ---------------------------------------------------------------------------
__global__ __launch_bounds__(256) void pred_kernel(
    const _Float16* __restrict__ Zot, const float* __restrict__ outTitle,
    const _Float16* __restrict__ Zol,
    const int* __restrict__ elSrc, const int* __restrict__ elDst,
    float* __restrict__ pred, int E)
{
    int idx = blockIdx.x * 256 + threadIdx.x;
    int e = idx >> 5;
    if (e >= E) return;
    int l = idx & 31;
    int s = elSrc[e];
    int d = elDst[e];
    f16x4 b = *reinterpret_cast<const f16x4*>(Zol + (size_t)d * D + l * 4);
    float v;
    if (Zot) {
        f16x4 a = *reinterpret_cast<const f16x4*>(Zot + (size_t)s * D + l * 4);
        v = (float)a[0] * (float)b[0] + (float)a[1] * (float)b[1]
          + (float)a[2] * (float)b[2] + (float)a[3] * (float)b[3];
    } else {
        const float* at = outTitle + (size_t)s * D + (l & 7) * 16 + (l >> 3) * 4;
        float4 a = *reinterpret_cast<const float4*>(at);
        v = a.x * (float)b[0] + a.y * (float)b[1]
          + a.z * (float)b[2] + a.w * (float)b[3];
    }
#pragma unroll
    for (int off = 16; off > 0; off >>= 1) v += __shfl_down(v, off, 32);
    if (l == 0) pred[e] = v;
}

// ---------------------------------------------------------------------------
extern "C" void kernel_launch(void* const* d_in, const int* in_sizes, int n_in,
                              void* d_out, int out_size, void* d_ws, size_t ws_size,
                              hipStream_t stream)
{
    const float* x_title       = (const float*)d_in[0];
    const float* label_embed   = (const float*)d_in[1];
    const float* W_l_tl        = (const float*)d_in[2];
    const float* b_l_tl        = (const float*)d_in[3];
    const float* W_r_tl        = (const float*)d_in[4];
    const float* W_l_ll        = (const float*)d_in[5];
    const float* b_l_ll        = (const float*)d_in[6];
    const float* W_r_ll        = (const float*)d_in[7];
    const int*   label_node_id = (const int*)d_in[8];
    const int*   ta_src        = (const int*)d_in[9];
    const int*   ta_dst        = (const int*)d_in[10];
    const int*   rev_src       = (const int*)d_in[11];
    const int*   rev_dst       = (const int*)d_in[12];
    const int*   ll_src        = (const int*)d_in[13];
    const int*   ll_dst        = (const int*)d_in[14];
    const int*   el_src        = (const int*)d_in[15];
    const int*   el_dst        = (const int*)d_in[16];

    float* out       = (float*)d_out;
    float* pred      = out;                        // [ELBL]
    float* out_title = out + ELBL;                 // [NT*D] — hosts meanRev first
    float* out_label = out_title + (size_t)NT * D; // [NL*D]

    // Workspace layout (~103 MB mandatory, +51.2 MB optional Zot).
    char* p = (char*)d_ws;
    __bf16*   Wb      = (__bf16*)p;            p += (size_t)4 * DD * sizeof(__bf16);
    float*    bias_sum= (float*)p;             p += D * sizeof(float);
    _Float16* Zta     = (_Float16*)p;          p += (size_t)NT * D * sizeof(_Float16);
    _Float16* Zrev    = Zta;                   // Zrev dies before Zta is born
    _Float16* Zll     = (_Float16*)p;          p += (size_t)NL * D * sizeof(_Float16);
    _Float16* Zol     = Zll;                   // Zol overlays dead Zll
    _Float16* meanTa  = (_Float16*)p;          p += (size_t)NL * D * sizeof(_Float16);
    _Float16* meanLl  = (_Float16*)p;          p += (size_t)NL * D * sizeof(_Float16);
    // pairs buffers overlay meanTa/meanLl (dead until agg_ta_ll).
    int2*     pTa     = (int2*)meanTa;
    int2*     pLl     = (int2*)(pTa + ETA);
    int2*     pRev    = (int2*)(pLl + ELL);
    int*      cntTa   = (int*)p;               p += NL * sizeof(int);
    int*      cntLl   = (int*)p;               p += NL * sizeof(int);
    int*      cntRev  = (int*)p;               p += NT * sizeof(int);
    int*      curTa   = (int*)p;               p += NL * sizeof(int);
    int*      curLl   = (int*)p;               p += NL * sizeof(int);
    int*      curRev  = (int*)p;               p += NT * sizeof(int);
    int*      csrTa   = (int*)p;               p += ETA * sizeof(int);
    int*      csrLl   = (int*)p;               p += ELL * sizeof(int);
    int*      csrRev  = (int*)p;               p += EREV * sizeof(int);
    int*      MTa     = (int*)p;               p += (size_t)NCH_TA * NBK * sizeof(int);
    int*      MLl     = (int*)p;               p += (size_t)NCH_LL * NBK * sizeof(int);
    int*      MRev    = (int*)p;               p += (size_t)NCH_REV * NBK * sizeof(int);
    int*      bsTa    = (int*)p;               p += (NBK + 1) * sizeof(int);
    int*      bsLl    = (int*)p;               p += (NBK + 1) * sizeof(int);
    int*      bsRev   = (int*)p;               p += (NBK + 1) * sizeof(int);
    _Float16* Zot     = (_Float16*)p;          p += (size_t)NT * D * sizeof(_Float16);
    if ((size_t)(p - (char*)d_ws) > ws_size) Zot = nullptr;   // pred falls back

    prep_weights<<<(DD + 255) / 256, 256, 0, stream>>>(
        W_l_tl, W_r_tl, W_l_ll, W_r_ll, b_l_tl, b_l_ll, Wb, bias_sum);

    z_label_gemm<<<(NL + 127) / 128, 512, 0, stream>>>(
        label_embed, label_node_id, Wb, Zrev, Zll);

    // Bucketed CSR build (LDS atomics only, bucket-local writes).
    part_count<<<NCH_TA + NCH_LL + NCH_REV, 256, 0, stream>>>(
        ta_dst, ll_dst, rev_dst, MTa, MLl, MRev);
    part_scan<<<3, 256, 0, stream>>>(MTa, MLl, MRev, bsTa, bsLl, bsRev);
    part_scatter<<<NCH_TA + NCH_LL + NCH_REV, 256, 0, stream>>>(
        ta_src, ta_dst, ll_src, ll_dst, rev_src, rev_dst,
        MTa, MLl, MRev, bsTa, bsLl, bsRev, pTa, pLl, pRev);
    csr_build<<<3 * NBK, 256, 0, stream>>>(
        pTa, bsTa, cntTa, curTa, csrTa,
        pLl, bsLl, cntLl, curLl, csrLl,
        pRev, bsRev, cntRev, curRev, csrRev);

    // rev mean: column-split 2-pass, fp32 permuted into outTitle region.
    agg_rev_kernel<<<2 * HREV, 256, 0, stream>>>(
        Zrev, csrRev, cntRev, curRev, out_title);

    // Title GEMM (512 threads; LDS weights; streams meanRev).
    gemm_title_mfma<<<(NT + 127) / 128, 512, 0, stream>>>(
        x_title, Wb, b_l_tl, Zta, Zot, out_title);

    // ta + ll means (fused).
    agg_ta_ll_kernel<<<2 * BTA, 256, 0, stream>>>(
        Zta, csrTa, cntTa, curTa, meanTa,
        Zll, csrLl, cntLl, curLl, meanLl);

    // Label GEMM (LDS weights; writes outLabel + Zol over dead Zll).
    gemm_label_mfma<<<(NL + 63) / 64, 256, 0, stream>>>(
        label_embed, label_node_id, Wb, bias_sum, meanTa, meanLl,
        out_label, Zol);

    pred_kernel<<<(ELBL * 32) / 256, 256, 0, stream>>>(
        Zot, out_title, Zol, el_src, el_dst, pred, ELBL);
}